// Round 8
// baseline (484.888 us; speedup 1.0000x reference)
//
#include <hip/hip_runtime.h>
#include <math.h>

// ---------------------------------------------------------------------------
// Decoder_82764019794508: LIIF-style decoder.
// R8: locality sort for the decoder gather. R7 showed the random gather is
// L2-capacity-miss bound (91 MB fetch for a 14 MB aspp). Counting-sort the
// 295k queries by corner-0 16x16 aspp tile (288 buckets), pre-pack per-query
// data, and XCD-swizzle decoder blocks so each tile is served by one XCD's L2.
// Decoder MFMA core + conv pipeline numerics unchanged from R7.
// ---------------------------------------------------------------------------

#define HQ 384
#define HA 192
#define NQ (2 * HQ * HQ)   // 294912 queries

typedef _Float16 half8  __attribute__((ext_vector_type(8)));
typedef _Float16 half4v __attribute__((ext_vector_type(4)));
typedef float    float4v __attribute__((ext_vector_type(4)));

// bucket id from query coords: corner k=0 (vy=vx=-1) pixel, 16x16 tiles
__device__ __forceinline__ int bucket_id(int q, float cy, float cx) {
    const float LO = -1.0f + 1e-7f, HI = 1.0f - 1e-7f;
    const float RXY = 1.0f / (float)HA;
    float c0 = fminf(fmaxf((cy - RXY) + 1e-7f, LO), HI);
    float c1 = fminf(fmaxf((cx - RXY) + 1e-7f, LO), HI);
    int iy = (int)rintf(((c0 + 1.f) * (float)HA) * 0.5f - 0.5f);
    int ix = (int)rintf(((c1 + 1.f) * (float)HA) * 0.5f - 0.5f);
    iy = min(max(iy, 0), HA - 1);
    ix = min(max(ix, 0), HA - 1);
    int b = q / (HQ * HQ);
    return b * 144 + (iy >> 4) * 12 + (ix >> 4);
}

// ---- K0: pack ALL weights into per-lane MFMA B-fragments + zero hist ------
__global__ void prep_all(const float* __restrict__ mw0,
                         const float* __restrict__ mw1,
                         const float* __restrict__ wf,
                         _Float16* __restrict__ fragTab,
                         _Float16* __restrict__ fragTabW,
                         int* __restrict__ hist) {
    int t = blockIdx.x * 256 + threadIdx.x;
    if (t < 1536) {
        int f = t >> 6, L = t & 63;
        int n_ = L & 15, qd = L >> 4;
        _Float16 vals[8];
        if (f < 16) {
            int kc = f >> 2, nt = f & 3;
#pragma unroll
            for (int j = 0; j < 8; ++j) {
                int kk = kc * 32 + qd * 8 + j;
                vals[j] = (_Float16)((kk < 102) ? mw0[kk * 64 + nt * 16 + n_] : 0.f);
            }
        } else {
            int g = f - 16;
            int kc = g >> 2, nt = g & 3;
#pragma unroll
            for (int j = 0; j < 8; ++j) {
                int kk = kc * 32 + qd * 8 + j;
                vals[j] = (_Float16)mw1[kk * 64 + nt * 16 + n_];
            }
        }
#pragma unroll
        for (int j = 0; j < 8; ++j) fragTab[t * 8 + j] = vals[j];
    } else {
        int tw = t - 1536;
        if (tw < 27 * 6 * 64) {
            int s   = tw / 384;
            int rem = tw - s * 384;
            int nt  = rem >> 6;
            int L   = rem & 63;
            int n_  = L & 15, qd = L >> 4;
            int tap = s / 3, kc = s - tap * 3;
#pragma unroll
            for (int j = 0; j < 8; ++j) {
                int kch = kc * 32 + qd * 8 + j;
                fragTabW[tw * 8 + j] =
                    (_Float16)wf[(tap * 96 + kch) * 96 + nt * 16 + n_];
            }
        } else if (tw < 27 * 6 * 64 + 288) {
            hist[tw - 27 * 6 * 64] = 0;   // ws is poisoned 0xAA each launch
        }
    }
}

// ---- K_s1: per-block LDS histogram of bucket ids --------------------------
__global__ void sort_hist(const float* __restrict__ coords,
                          int* __restrict__ hist) {
    __shared__ int lh[288];
    const int tid = threadIdx.x;
    for (int i = tid; i < 288; i += 256) lh[i] = 0;
    __syncthreads();
    const int q = blockIdx.x * 256 + tid;
    float cy = coords[(size_t)q * 2 + 0];
    float cx = coords[(size_t)q * 2 + 1];
    atomicAdd(&lh[bucket_id(q, cy, cx)], 1);
    __syncthreads();
    for (int i = tid; i < 288; i += 256) atomicAdd(&hist[i], lh[i]);
}

// ---- K_s2: exclusive scan over 288 buckets (one 512-thread block) ---------
__global__ void sort_scan(const int* __restrict__ hist,
                          int* __restrict__ cursor) {
    __shared__ int s[512];
    const int t = threadIdx.x;
    int v = (t < 288) ? hist[t] : 0;
    s[t] = v;
    __syncthreads();
    for (int off = 1; off < 512; off <<= 1) {
        int x = (t >= off) ? s[t - off] : 0;
        __syncthreads();
        s[t] += x;
        __syncthreads();
    }
    if (t < 288) cursor[t] = s[t] - v;   // exclusive
}

// ---- K_s3: scatter query indices + packed per-query data ------------------
__global__ void sort_scatter(const float* __restrict__ coords,
                             const float* __restrict__ cells,
                             int* __restrict__ cursor,
                             int* __restrict__ qidx,
                             float4v* __restrict__ qdata) {
    const int q = blockIdx.x * 256 + threadIdx.x;
    float cy = coords[(size_t)q * 2 + 0];
    float cx = coords[(size_t)q * 2 + 1];
    int pos = atomicAdd(&cursor[bucket_id(q, cy, cx)], 1);
    qidx[pos] = q;
    float4v d = {cy, cx,
                 cells[(size_t)q * 2 + 0] * (float)HA,
                 cells[(size_t)q * 2 + 1] * (float)HA};
    qdata[pos] = d;
}

// ---- K1: fused 1x1 convs for a4s (96->32) and a32s (160->32), fp32 out ----
__global__ void conv1x1_ab(const float* __restrict__ feats4,
                           const float* __restrict__ w4,
                           const float* __restrict__ b4,
                           const float* __restrict__ feats32,
                           const float* __restrict__ w32,
                           const float* __restrict__ b32,
                           float* __restrict__ a4s,
                           float* __restrict__ a32s) {
    int blk = blockIdx.x;
    if (blk < 2304) {
        int t = blk * 256 + threadIdx.x;
        int p = t >> 5, c = t & 31;
        const float* xr = feats4 + (size_t)p * 96;
        float acc = b4[c];
#pragma unroll
        for (int i = 0; i < 96; ++i) acc = fmaf(xr[i], w4[i * 32 + c], acc);
        a4s[(size_t)p * 32 + c] = fmaxf(acc, 0.f);
    } else {
        int t = (blk - 2304) * 256 + threadIdx.x;
        int p = t >> 5, c = t & 31;
        const float* xr = feats32 + (size_t)p * 160;
        float acc = b32[c];
#pragma unroll
        for (int i = 0; i < 160; ++i) acc = fmaf(xr[i], w32[i * 32 + c], acc);
        a32s[(size_t)p * 32 + c] = fmaxf(acc, 0.f);
    }
}

// ---- K2: build xcat (fp16), 3 slices selected by blockIdx.y ---------------
__global__ void build_xcat(const float* __restrict__ feats2,
                           const float* __restrict__ w2,
                           const float* __restrict__ b2,
                           const float* __restrict__ a4s,
                           const float* __restrict__ a32s,
                           _Float16* __restrict__ xcatH) {
    const int z = blockIdx.y;
    int t = blockIdx.x * 256 + threadIdx.x;
    int c = t & 31;
    int p = t >> 5;

    if (z == 0) {
        const float* xr = feats2 + (size_t)p * 64;
        float acc = b2[c];
#pragma unroll
        for (int i = 0; i < 64; ++i) acc = fmaf(xr[i], w2[i * 32 + c], acc);
        xcatH[(size_t)p * 96 + c] = (_Float16)fmaxf(acc, 0.f);
        return;
    }

    const float* src = (z == 1) ? a4s : a32s;
    const int   S    = (z == 1) ? 96 : 24;
    const float inv  = (z == 1) ? 0.5f : 0.125f;
    const int   coff = (z == 1) ? 32 : 64;

    int x = p % HA;
    int r = p / HA;
    int y = r % HA;
    int b = r / HA;

    float u = ((float)y + 0.5f) * inv - 0.5f;
    float v = ((float)x + 0.5f) * inv - 0.5f;
    float fu = floorf(u), fv = floorf(v);
    float wu = u - fu, wv = v - fv;
    int y0 = (int)fu, x0 = (int)fv;
    int y1 = min(y0 + 1, S - 1);
    int x1 = min(x0 + 1, S - 1);
    y0 = max(y0, 0);
    x0 = max(x0, 0);

    const float* sb = src + (size_t)b * S * S * 32 + c;
    float v00 = sb[(y0 * S + x0) * 32];
    float v01 = sb[(y0 * S + x1) * 32];
    float v10 = sb[(y1 * S + x0) * 32];
    float v11 = sb[(y1 * S + x1) * 32];
    float t0 = v00 * (1.f - wu) + v10 * wu;
    float t1 = v01 * (1.f - wu) + v11 * wu;
    float o  = t0 * (1.f - wv) + t1 * wv;
    xcatH[(size_t)p * 96 + coff + c] = (_Float16)o;
}

// ---- K3: 3x3 conv 96->96 + bias + ReLU via fp16 MFMA, fp16 in/out ---------
__launch_bounds__(256, 4)
__global__ void conv3x3_mfma(const _Float16* __restrict__ xH,
                             const _Float16* __restrict__ fragTabW,
                             const float* __restrict__ bias,
                             _Float16* __restrict__ yH) {
    __shared__ _Float16 lds[10 * 18 * 104];
    const int tid = threadIdx.x;
    const int lane = tid & 63;
    const int wv   = tid >> 6;
    const int n_   = lane & 15;
    const int qd   = lane >> 4;
    const int nh   = wv & 1;
    const int yg   = wv >> 1;
    const int bx0  = blockIdx.x * 16;
    const int by0  = blockIdx.y * 8;
    const int b    = blockIdx.z;

    for (int idx = tid; idx < 2160; idx += 256) {
        int hy  = idx / 216;
        int rem = idx - hy * 216;
        int hx  = rem / 12;
        int cc  = rem - hx * 12;
        int gy = by0 + hy - 1, gx = bx0 + hx - 1;
        half8 v = {(_Float16)0.f, (_Float16)0.f, (_Float16)0.f, (_Float16)0.f,
                   (_Float16)0.f, (_Float16)0.f, (_Float16)0.f, (_Float16)0.f};
        if (gy >= 0 && gy < HA && gx >= 0 && gx < HA)
            v = *(const half8*)(xH + (((size_t)b * HA + gy) * HA + gx) * 96 + cc * 8);
        *(half8*)&lds[(hy * 18 + hx) * 104 + cc * 8] = v;
    }

    float bv[3];
#pragma unroll
    for (int j = 0; j < 3; ++j) bv[j] = bias[(nh * 3 + j) * 16 + n_];

    __syncthreads();

    float4v acc[4][3];
#pragma unroll
    for (int r = 0; r < 4; ++r)
#pragma unroll
        for (int j = 0; j < 3; ++j) {
            float4v z = {0.f, 0.f, 0.f, 0.f};
            acc[r][j] = z;
        }

#pragma unroll 1
    for (int ky = 0; ky < 3; ++ky)
#pragma unroll 1
        for (int kx = 0; kx < 3; ++kx) {
            const int tap = ky * 3 + kx;
#pragma unroll
            for (int kc = 0; kc < 3; ++kc) {
                const int s = tap * 3 + kc;
                half8 bf[3];
#pragma unroll
                for (int j = 0; j < 3; ++j)
                    bf[j] = *(const half8*)(fragTabW +
                            ((size_t)(s * 6 + nh * 3 + j) * 64 + lane) * 8);
#pragma unroll
                for (int r = 0; r < 4; ++r) {
                    const int yr = yg * 4 + r;
                    half8 a = *(const half8*)&lds[((yr + ky) * 18 + (n_ + kx)) * 104
                                                  + kc * 32 + qd * 8];
#pragma unroll
                    for (int j = 0; j < 3; ++j)
                        acc[r][j] = __builtin_amdgcn_mfma_f32_16x16x32_f16(
                            a, bf[j], acc[r][j], 0, 0, 0);
                }
            }
        }

#pragma unroll
    for (int r = 0; r < 4; ++r) {
        const int gy = by0 + yg * 4 + r;
#pragma unroll
        for (int j = 0; j < 3; ++j) {
            const int ch = (nh * 3 + j) * 16 + n_;
#pragma unroll
            for (int reg = 0; reg < 4; ++reg) {
                const int gx = bx0 + qd * 4 + reg;
                yH[(((size_t)b * HA + gy) * HA + gx) * 96 + ch] =
                    (_Float16)fmaxf(acc[r][j][reg] + bv[j], 0.f);
            }
        }
    }
}

// ---- K4: sorted 4-corner gather + MLP ensemble via fp16 MFMA --------------
// Block handles sorted slots [r*32, r*32+32), r XCD-swizzled so consecutive
// sorted ranges (same aspp tiles) share blockIdx%8 -> one XCD's L2.
__launch_bounds__(256, 3)
__global__ void decoder_mlp_mfma(const _Float16* __restrict__ asppH,
                                 const int* __restrict__ qidx,
                                 const float4v* __restrict__ qdata,
                                 const _Float16* __restrict__ fragTab,
                                 const float* __restrict__ mb0,
                                 const float* __restrict__ mb1,
                                 const float* __restrict__ mw2,
                                 const float* __restrict__ mb2,
                                 float* __restrict__ out) {
    __shared__ __align__(16) unsigned char smem[50688];
    _Float16* A   = (_Float16*)smem;              // 32768 B
    _Float16* Hb  = (_Float16*)(smem + 32768);    // 16384 B
    int*      pixL  = (int*)(smem + 49152);       // 512 B
    float*    areaL = (float*)(smem + 49664);     // 512 B
    float*    predL = (float*)(smem + 50176);     // 512 B

    const int tid  = threadIdx.x;
    const int lane = tid & 63;
    const int wv   = tid >> 6;
    const int n_   = lane & 15;
    const int qd   = lane >> 4;
    const int r    = (blockIdx.x & 7) * 1152 + (blockIdx.x >> 3);

    if (tid < 128) {
        const int lq = tid >> 2, k = tid & 3;
        const int sp = r * 32 + lq;
        const float4v d = qdata[sp];
        const int qq = qidx[sp];
        const int b  = qq / (HQ * HQ);
        const float cy = d[0], cx = d[1];
        const float rcy = d[2], rcx = d[3];

        const float LO = -1.0f + 1e-7f, HI = 1.0f - 1e-7f;
        const float RXY = 1.0f / (float)HA;
        const float vy = (k < 2) ? -1.f : 1.f;
        const float vx = (k & 1) ? 1.f : -1.f;

        float c0 = fminf(fmaxf((cy + vy * RXY) + 1e-7f, LO), HI);
        float c1 = fminf(fmaxf((cx + vx * RXY) + 1e-7f, LO), HI);
        int iy = (int)rintf(((c0 + 1.f) * (float)HA) * 0.5f - 0.5f);
        int ix = (int)rintf(((c1 + 1.f) * (float)HA) * 0.5f - 0.5f);
        iy = min(max(iy, 0), HA - 1);
        ix = min(max(ix, 0), HA - 1);

        const float cs0 = (((float)iy + 0.5f) / (float)HA) * 2.f - 1.f;
        const float cs1 = (((float)ix + 0.5f) / (float)HA) * 2.f - 1.f;
        const float r0 = (cy - cs0) * (float)HA;
        const float r1 = (cx - cs1) * (float)HA;

        pixL[tid]  = ((b * HA + iy) * HA + ix) * 96;
        areaL[tid] = fabsf(r0 * r1) + 1e-7f;

        const int row = tid;
        half8 e0;
        e0[0] = (_Float16)r0;  e0[1] = (_Float16)r1;
        e0[2] = (_Float16)cy;  e0[3] = (_Float16)cx;
        e0[4] = (_Float16)rcy; e0[5] = (_Float16)rcx;
        e0[6] = (_Float16)0.f; e0[7] = (_Float16)0.f;
        half8 z = {(_Float16)0.f, (_Float16)0.f, (_Float16)0.f, (_Float16)0.f,
                   (_Float16)0.f, (_Float16)0.f, (_Float16)0.f, (_Float16)0.f};
        *(half8*)&A[row * 128 + ((12 ^ (row & 15)) * 8)] = e0;
        *(half8*)&A[row * 128 + ((13 ^ (row & 15)) * 8)] = z;
        *(half8*)&A[row * 128 + ((14 ^ (row & 15)) * 8)] = z;
        *(half8*)&A[row * 128 + ((15 ^ (row & 15)) * 8)] = z;
    }

    half8 B0[16];
#pragma unroll
    for (int i = 0; i < 16; ++i)
        B0[i] = *(const half8*)(fragTab + ((size_t)i * 64 + lane) * 8);
    float mb0v[4], mb1v[4], w2v[4];
#pragma unroll
    for (int nt = 0; nt < 4; ++nt) {
        mb0v[nt] = mb0[nt * 16 + n_];
        mb1v[nt] = mb1[nt * 16 + n_];
        w2v[nt]  = mw2[nt * 16 + n_];
    }
    const float mb2s = mb2[0];

    __syncthreads();

    {
        const int grp = tid >> 4;
        const int l   = tid & 15;
#pragma unroll 1
        for (int it = 0; it < 8; ++it) {
            const int row  = it * 16 + grp;
            const int base = pixL[row];
            if (l < 12) {
                half8 h = *(const half8*)(asppH + base + l * 8);
                *(half8*)&A[row * 128 + ((l ^ (row & 15)) * 8)] = h;
            }
        }
    }
    __syncthreads();

#pragma unroll 1
    for (int mt = 0; mt < 2; ++mt) {
        const int m0  = wv * 32 + mt * 16;
        const int row = m0 + n_;

        float4v acc[4];
#pragma unroll
        for (int nt = 0; nt < 4; ++nt) {
            float4v t = {mb0v[nt], mb0v[nt], mb0v[nt], mb0v[nt]};
            acc[nt] = t;
        }
#pragma unroll
        for (int kc = 0; kc < 4; ++kc) {
            half8 a = *(const half8*)&A[row * 128 + (((kc * 4 + qd) ^ (row & 15)) * 8)];
#pragma unroll
            for (int nt = 0; nt < 4; ++nt)
                acc[nt] = __builtin_amdgcn_mfma_f32_16x16x32_f16(a, B0[kc * 4 + nt],
                                                                 acc[nt], 0, 0, 0);
        }
#pragma unroll
        for (int nt = 0; nt < 4; ++nt)
#pragma unroll
            for (int reg = 0; reg < 4; ++reg) {
                const int hr = m0 + qd * 4 + reg;
                const int n  = nt * 16 + n_;
                Hb[hr * 64 + (((n >> 3) ^ (hr & 7)) * 8) + (n & 7)] =
                    (_Float16)fmaxf(acc[nt][reg], 0.f);
            }
        __builtin_amdgcn_s_waitcnt(0);

        float4v acc1[4];
#pragma unroll
        for (int nt = 0; nt < 4; ++nt) {
            float4v t = {mb1v[nt], mb1v[nt], mb1v[nt], mb1v[nt]};
            acc1[nt] = t;
        }
#pragma unroll
        for (int kc = 0; kc < 2; ++kc) {
            half8 a1 = *(const half8*)&Hb[row * 64 + (((kc * 4 + qd) ^ (row & 7)) * 8)];
#pragma unroll
            for (int nt = 0; nt < 4; ++nt) {
                half8 b1 = *(const half8*)(fragTab +
                            ((size_t)(16 + kc * 4 + nt) * 64 + lane) * 8);
                acc1[nt] = __builtin_amdgcn_mfma_f32_16x16x32_f16(a1, b1,
                                                                  acc1[nt], 0, 0, 0);
            }
        }

        float p[4];
#pragma unroll
        for (int reg = 0; reg < 4; ++reg) {
            float s = 0.f;
#pragma unroll
            for (int nt = 0; nt < 4; ++nt)
                s = fmaf(fmaxf(acc1[nt][reg], 0.f), w2v[nt], s);
            s += __shfl_xor(s, 1, 64);
            s += __shfl_xor(s, 2, 64);
            s += __shfl_xor(s, 4, 64);
            s += __shfl_xor(s, 8, 64);
            p[reg] = s;
        }
        if (n_ == 0) {
            float4v pv = {p[0] + mb2s, p[1] + mb2s, p[2] + mb2s, p[3] + mb2s};
            *(float4v*)&predL[m0 + qd * 4] = pv;
        }
    }
    __syncthreads();

    if (tid < 32) {
        float4v pr = *(const float4v*)&predL[tid * 4];
        float4v ar = *(const float4v*)&areaL[tid * 4];
        float num = pr[0] * ar[3] + pr[1] * ar[2] + pr[2] * ar[1] + pr[3] * ar[0];
        float den = ar[0] + ar[1] + ar[2] + ar[3];
        out[qidx[r * 32 + tid]] = num / den;
    }
}

// ---------------------------------------------------------------------------
extern "C" void kernel_launch(void* const* d_in, const int* in_sizes, int n_in,
                              void* d_out, int out_size, void* d_ws, size_t ws_size,
                              hipStream_t stream) {
    (void)in_sizes; (void)n_in; (void)out_size; (void)ws_size;
    const float* feats2  = (const float*)d_in[0];
    const float* feats4  = (const float*)d_in[1];
    const float* feats32 = (const float*)d_in[2];
    const float* coords  = (const float*)d_in[3];
    const float* cells   = (const float*)d_in[4];
    const float* w2  = (const float*)d_in[5];
    const float* b2  = (const float*)d_in[6];
    const float* w4  = (const float*)d_in[7];
    const float* b4  = (const float*)d_in[8];
    const float* w32 = (const float*)d_in[9];
    const float* b32 = (const float*)d_in[10];
    const float* wf  = (const float*)d_in[11];
    const float* bf  = (const float*)d_in[12];
    const float* mw0 = (const float*)d_in[13];
    const float* mb0 = (const float*)d_in[14];
    const float* mw1 = (const float*)d_in[15];
    const float* mb1 = (const float*)d_in[16];
    const float* mw2 = (const float*)d_in[17];
    const float* mb2 = (const float*)d_in[18];

    float* ws = (float*)d_ws;
    float*    a4s   = ws;                          // 589824 f
    float*    a32s  = a4s + 589824;                // 36864 f
    _Float16* xcatH = (_Float16*)(a32s + 36864);   // 7,077,888 h
    _Float16* asppH = xcatH + 7077888;             // 7,077,888 h
    _Float16* fragTab  = asppH + 7077888;          // 12,288 h
    _Float16* fragTabW = fragTab + 12288;          // 82,944 h
    float4v*  qdata = (float4v*)(fragTabW + 82944);   // NQ * 16 B (16B-aligned)
    int*      qidx  = (int*)(qdata + NQ);             // NQ ints
    int*      hist  = qidx + NQ;                      // 288
    int*      cursor = hist + 288;                    // 288
    float* out = (float*)d_out;

    prep_all<<<48, 256, 0, stream>>>(mw0, mw1, wf, fragTab, fragTabW, hist);
    sort_hist<<<NQ / 256, 256, 0, stream>>>(coords, hist);
    sort_scan<<<1, 512, 0, stream>>>(hist, cursor);
    sort_scatter<<<NQ / 256, 256, 0, stream>>>(coords, cells, cursor, qidx, qdata);
    conv1x1_ab<<<2448, 256, 0, stream>>>(feats4, w4, b4, feats32, w32, b32,
                                         a4s, a32s);
    build_xcat<<<dim3(9216, 3), 256, 0, stream>>>(feats2, w2, b2, a4s, a32s,
                                                  xcatH);
    conv3x3_mfma<<<dim3(12, 24, 2), 256, 0, stream>>>(xcatH, fragTabW, bf, asppH);
    decoder_mlp_mfma<<<9216, 256, 0, stream>>>(asppH, qidx, qdata, fragTab,
                                               mb0, mb1, mw2, mb2, out);
}